// Round 5
// baseline (53.926 us; speedup 1.0000x reference)
//
#include <hip/hip_runtime.h>

typedef __bf16 bf16;
typedef __attribute__((ext_vector_type(4)))  __bf16 bf16x4;
typedef __attribute__((ext_vector_type(8)))  __bf16 bf16x8;
typedef __attribute__((ext_vector_type(4)))  float  f32x4;
typedef __attribute__((ext_vector_type(16))) float  f32x16;

constexpr int B_ = 16, N_ = 256, K_ = 10, C_ = 100, CP_ = 112;
constexpr float NL2E = -0.7213475204444817f;             // -0.5*log2(e)
constexpr size_t XKT_ELEMS = (size_t)B_ * K_ * CP_ * N_; // 4,587,520 bf16
constexpr size_t AG_ELEMS  = (size_t)B_ * K_ * N_ * N_;  // 10,485,760 bf16
constexpr size_t AG_OFF = XKT_ELEMS;
constexpr size_t WP_OFF = XKT_ELEMS + AG_ELEMS;          // Wp: [112][128] bf16
constexpr size_t CF_OFF_BYTES = (WP_OFF + 112 * 128) * 2; // 4B-aligned f32 coefs

// ---------------------------------------------------------------------------
// setup: Wp (bf16 zero-padded W) + per-k gaussian coefs [K][12]:
//   alpha_d (x4), beta_d (x4), gamma, pad(3);  s_log2 = gamma + sum alpha*p^2 + beta*p
// ---------------------------------------------------------------------------
__global__ __launch_bounds__(256) void setup_k(
    const float* __restrict__ W, const float* __restrict__ mu,
    const float* __restrict__ sigma, bf16* __restrict__ ws)
{
    const int bid = blockIdx.x, tid = threadIdx.x;
    if (bid < 56) {
        int idx = bid * 256 + tid;                 // covers 112*128
        int c = idx >> 7, j = idx & 127;
        ws[WP_OFF + idx] = (bf16)((c < C_ && j < C_) ? W[c * C_ + j] : 0.0f);
    } else if (tid < K_) {
        float* cf = (float*)((char*)ws + CF_OFF_BYTES);
        float ga = 0.0f;
        #pragma unroll
        for (int d = 0; d < 4; ++d) {
            float sg = sigma[tid * 4 + d];
            float al = NL2E / (1e-6f + sg * sg);
            float mv = mu[tid * 4 + d];
            cf[tid * 12 + d]     = al;
            cf[tid * 12 + 4 + d] = -2.0f * al * mv;
            ga += al * mv * mv;
        }
        cf[tid * 12 + 8] = ga;
        cf[tid * 12 + 9] = 0.0f; cf[tid * 12 + 10] = 0.0f; cf[tid * 12 + 11] = 0.0f;
    }
}

// ---------------------------------------------------------------------------
// prep (hetero, no LDS, no barriers):
//  blocks [0,640):    xkT[b,k][c][m] via MFMA 16x16x32, A = Wp from global
//  blocks [640,1664): ag[b,k][n][m] = adj * exp2(quadratic), coefs from ws
// ---------------------------------------------------------------------------
__global__ __launch_bounds__(256) void prep(
    const float* __restrict__ x, const float* __restrict__ adj,
    const float* __restrict__ pseudo, const float* __restrict__ bias,
    bf16* __restrict__ ws)
{
    const int bid = blockIdx.x, tid = threadIdx.x;

    if (bid < 640) {
        // ------------------- xkT GEMM part -------------------
        const bf16* Wp = ws + WP_OFF;
        const int xcd = bid & 7, s = bid >> 3;     // s: 0..79
        const int b  = xcd + 8 * (s / 40);
        const int rr = s % 40, kk = rr >> 2, mh = rr & 3;
        const int w = tid >> 6, l = tid & 63, l15 = l & 15, g = l >> 4;
        const int m = mh * 64 + w * 16 + l15;
        const float* xp = x + ((size_t)(b * N_ + m) * K_ + kk) * C_;

        f32x4 acc[7];
        #pragma unroll
        for (int ct = 0; ct < 7; ++ct)
            #pragma unroll
            for (int r = 0; r < 4; ++r) {
                int c = ct * 16 + g * 4 + r;
                acc[ct][r] = (c < C_) ? bias[c] : 0.0f;
            }

        #pragma unroll
        for (int ks = 0; ks < 4; ++ks) {
            const int jb = ks * 32 + g * 8;
            bf16x8 bfr;
            #pragma unroll
            for (int i = 0; i < 8; ++i) bfr[i] = (bf16)0.0f;
            if (jb + 8 <= C_) {
                float4 x0 = *(const float4*)(xp + jb);
                float4 x1 = *(const float4*)(xp + jb + 4);
                bfr[0]=(bf16)x0.x; bfr[1]=(bf16)x0.y; bfr[2]=(bf16)x0.z; bfr[3]=(bf16)x0.w;
                bfr[4]=(bf16)x1.x; bfr[5]=(bf16)x1.y; bfr[6]=(bf16)x1.z; bfr[7]=(bf16)x1.w;
            } else if (jb < C_) {                  // jb == 96
                float4 x0 = *(const float4*)(xp + jb);
                bfr[0]=(bf16)x0.x; bfr[1]=(bf16)x0.y; bfr[2]=(bf16)x0.z; bfr[3]=(bf16)x0.w;
            }
            #pragma unroll
            for (int ct = 0; ct < 7; ++ct) {
                bf16x8 af = *(const bf16x8*)(Wp + (size_t)(ct * 16 + l15) * 128 + jb);
                acc[ct] = __builtin_amdgcn_mfma_f32_16x16x32_bf16(af, bfr, acc[ct], 0, 0, 0);
            }
        }

        bf16* op = ws + (size_t)(b * K_ + kk) * CP_ * N_;
        #pragma unroll
        for (int ct = 0; ct < 7; ++ct)
            #pragma unroll
            for (int r = 0; r < 4; ++r)
                op[(size_t)(ct * 16 + g * 4 + r) * N_ + m] = (bf16)acc[ct][r];
    } else {
        // ------------------- gaussian ag part -------------------
        const float* cf = (const float*)((const char*)ws + CF_OFF_BYTES);
        const int a = bid - 640;                   // 0..1023
        const int xcd = a & 7, u = a >> 3;         // u: 0..127
        const int b = xcd + 8 * (u & 1);
        const int n = (u >> 1) * 4 + (tid >> 6);
        const int m = (tid & 63) * 4;

        const float* pp = pseudo + ((size_t)(b * N_ + n) * N_ + m) * 4;
        float4 p0 = *(const float4*)(pp + 0);
        float4 p1 = *(const float4*)(pp + 4);
        float4 p2 = *(const float4*)(pp + 8);
        float4 p3 = *(const float4*)(pp + 12);
        float4 av = *(const float4*)(adj + (size_t)(b * N_ + n) * N_ + m);

        float4 q0 = {p0.x*p0.x, p0.y*p0.y, p0.z*p0.z, p0.w*p0.w};
        float4 q1 = {p1.x*p1.x, p1.y*p1.y, p1.z*p1.z, p1.w*p1.w};
        float4 q2 = {p2.x*p2.x, p2.y*p2.y, p2.z*p2.z, p2.w*p2.w};
        float4 q3 = {p3.x*p3.x, p3.y*p3.y, p3.z*p3.z, p3.w*p3.w};

        bf16* agb = ws + AG_OFF;
        #pragma unroll
        for (int k = 0; k < K_; ++k) {
            f32x4 A = *(const f32x4*)(cf + k * 12);
            f32x4 Bv = *(const f32x4*)(cf + k * 12 + 4);
            float ga = cf[k * 12 + 8];

            float s0 = ga + A[0]*q0.x + Bv[0]*p0.x + A[1]*q0.y + Bv[1]*p0.y
                          + A[2]*q0.z + Bv[2]*p0.z + A[3]*q0.w + Bv[3]*p0.w;
            float s1 = ga + A[0]*q1.x + Bv[0]*p1.x + A[1]*q1.y + Bv[1]*p1.y
                          + A[2]*q1.z + Bv[2]*p1.z + A[3]*q1.w + Bv[3]*p1.w;
            float s2 = ga + A[0]*q2.x + Bv[0]*p2.x + A[1]*q2.y + Bv[1]*p2.y
                          + A[2]*q2.z + Bv[2]*p2.z + A[3]*q2.w + Bv[3]*p2.w;
            float s3 = ga + A[0]*q3.x + Bv[0]*p3.x + A[1]*q3.y + Bv[1]*p3.y
                          + A[2]*q3.z + Bv[2]*p3.z + A[3]*q3.w + Bv[3]*p3.w;

            float g0 = __builtin_amdgcn_exp2f(s0) * av.x;
            float g1 = __builtin_amdgcn_exp2f(s1) * av.y;
            float g2 = __builtin_amdgcn_exp2f(s2) * av.z;
            float g3 = __builtin_amdgcn_exp2f(s3) * av.w;

            bf16x4 o = {(bf16)g0, (bf16)g1, (bf16)g2, (bf16)g3};
            *(bf16x4*)(agb + ((size_t)(b * K_ + k) * N_ + n) * N_ + m) = o;
        }
    }
}

// ---------------------------------------------------------------------------
// agg_gemm: out[b,k][c][n] = sum_m ag[n,m]*xk[m,c].  MFMA 32x32x16.
//   Block = (b, k, n32-tile); wave w owns c-tile w (rows w*32..w*32+31).
//   Grid 1280 XCD-swizzled blocks x 4 waves = 5120 waves.
//   c rows 100..111 are zeros; 112..127 overread garbage -> cols not stored.
// ---------------------------------------------------------------------------
__global__ __launch_bounds__(256) void agg_gemm(
    const bf16* __restrict__ ws, float* __restrict__ out)
{
    const int bid = blockIdx.x;
    const int xcd = bid & 7, s = bid >> 3;         // s: 0..159
    const int b  = xcd + 8 * (s / 80);
    const int rr = s % 80, kk = rr >> 3, nh = rr & 7;
    const int tid = threadIdx.x;
    const int w = tid >> 6, l = tid & 63, l31 = l & 31, h = l >> 5;
    const int n32 = nh * 32;

    const bf16* arow = ws + AG_OFF + ((size_t)(b * K_ + kk) * N_ + n32 + l31) * N_;
    const bf16* brow = ws + (size_t)(b * K_ + kk) * CP_ * N_ + (size_t)(w * 32 + l31) * N_;

    f32x16 acc;
    #pragma unroll
    for (int i = 0; i < 16; ++i) acc[i] = 0.0f;

    #pragma unroll
    for (int ks = 0; ks < 16; ++ks) {
        const int m0 = ks * 16 + h * 8;
        bf16x8 af = *(const bf16x8*)(arow + m0);
        bf16x8 bf = *(const bf16x8*)(brow + m0);
        acc = __builtin_amdgcn_mfma_f32_32x32x16_bf16(af, bf, acc, 0, 0, 0);
    }

    const int c = w * 32 + l31;
    if (c < C_) {
        float* ob = out + (size_t)(b * K_ + kk) * C_ * N_ + (size_t)c * N_ + n32;
        #pragma unroll
        for (int q = 0; q < 4; ++q) {
            float4 v = {acc[4*q+0], acc[4*q+1], acc[4*q+2], acc[4*q+3]};
            *(float4*)(ob + 8 * q + 4 * h) = v;
        }
    }
}

extern "C" void kernel_launch(void* const* d_in, const int* in_sizes, int n_in,
                              void* d_out, int out_size, void* d_ws, size_t ws_size,
                              hipStream_t stream)
{
    const float* x      = (const float*)d_in[0];
    const float* adj    = (const float*)d_in[1];
    const float* pseudo = (const float*)d_in[2];
    const float* mu     = (const float*)d_in[3];
    const float* sigma  = (const float*)d_in[4];
    const float* W      = (const float*)d_in[5];
    const float* bias   = (const float*)d_in[6];
    float* out = (float*)d_out;
    bf16* ws   = (bf16*)d_ws;   // xkT | ag | Wp | coefs  (~30.2 MB)

    hipLaunchKernelGGL(setup_k, dim3(57), dim3(256), 0, stream, W, mu, sigma, ws);
    hipLaunchKernelGGL(prep, dim3(1664), dim3(256), 0, stream,
                       x, adj, pseudo, bias, ws);
    hipLaunchKernelGGL(agg_gemm, dim3(1280), dim3(256), 0, stream, ws, out);
}

// Round 6
// 44.776 us; speedup vs baseline: 1.2043x; 1.2043x over previous
//
#include <hip/hip_runtime.h>

typedef __bf16 bf16;
typedef __attribute__((ext_vector_type(4)))  __bf16 bf16x4;
typedef __attribute__((ext_vector_type(8)))  __bf16 bf16x8;
typedef __attribute__((ext_vector_type(4)))  float  f32x4;
typedef __attribute__((ext_vector_type(16))) float  f32x16;

constexpr int B_ = 16, N_ = 256, K_ = 10, C_ = 100, CP_ = 112;
constexpr float NL2E = -0.7213475204444817f;             // -0.5*log2(e)

__device__ inline bf16x8 cvt8(const float* p) {
    float4 a = *(const float4*)p, b = *(const float4*)(p + 4);
    bf16x8 r = {(bf16)a.x, (bf16)a.y, (bf16)a.z, (bf16)a.w,
                (bf16)b.x, (bf16)b.y, (bf16)b.z, (bf16)b.w};
    return r;
}
__device__ inline bf16x8 cvt4z(const float* p) {          // 4 valid + 4 zeros
    float4 a = *(const float4*)p;
    bf16x8 r = {(bf16)a.x, (bf16)a.y, (bf16)a.z, (bf16)a.w,
                (bf16)0.0f, (bf16)0.0f, (bf16)0.0f, (bf16)0.0f};
    return r;
}

// ---------------------------------------------------------------------------
// K1: xkT[b,k][c(112)][m] = sum_j W[c,j]*x[b,m,k*C+j] + bias[c]   (bf16)
//   MFMA 16x16x32. W read f32 + cvt in registers (no setup kernel, no LDS,
//   no barriers). Rows c in [100,112) written as zeros (K2 reads them).
// Grid 640 XCD-swizzled blocks x 256 thr.
// ---------------------------------------------------------------------------
__global__ __launch_bounds__(256) void xk_gemm(
    const float* __restrict__ x, const float* __restrict__ W,
    const float* __restrict__ bias, bf16* __restrict__ xkT)
{
    const int bid = blockIdx.x;
    const int xcd = bid & 7, s = bid >> 3;         // s: 0..79
    const int b  = xcd + 8 * (s / 40);
    const int rr = s % 40, kk = rr >> 2, mh = rr & 3;
    const int tid = threadIdx.x;
    const int w = tid >> 6, l = tid & 63, l15 = l & 15, g = l >> 4;
    const int m = mh * 64 + w * 16 + l15;
    const float* xp = x + ((size_t)(b * N_ + m) * K_ + kk) * C_;

    f32x4 acc[7];
    #pragma unroll
    for (int ct = 0; ct < 7; ++ct)
        #pragma unroll
        for (int r = 0; r < 4; ++r) {
            int c = ct * 16 + g * 4 + r;
            acc[ct][r] = (c < C_) ? bias[c] : 0.0f;
        }

    const bf16x8 zf = {(bf16)0.f,(bf16)0.f,(bf16)0.f,(bf16)0.f,
                       (bf16)0.f,(bf16)0.f,(bf16)0.f,(bf16)0.f};

    #pragma unroll
    for (int ks = 0; ks < 4; ++ks) {
        const int jb = ks * 32 + g * 8;
        bf16x8 bfr = zf;
        if (jb + 8 <= C_)      bfr = cvt8(xp + jb);
        else if (jb < C_)      bfr = cvt4z(xp + jb);       // jb == 96
        #pragma unroll
        for (int ct = 0; ct < 7; ++ct) {
            const int c = ct * 16 + l15;
            bf16x8 af = zf;
            if (c < C_) {
                if (jb + 8 <= C_) af = cvt8(W + (size_t)c * C_ + jb);
                else if (jb < C_) af = cvt4z(W + (size_t)c * C_ + jb);
            }
            acc[ct] = __builtin_amdgcn_mfma_f32_16x16x32_bf16(af, bfr, acc[ct], 0, 0, 0);
        }
    }

    bf16* op = xkT + (size_t)(b * K_ + kk) * CP_ * N_;
    #pragma unroll
    for (int ct = 0; ct < 7; ++ct)
        #pragma unroll
        for (int r = 0; r < 4; ++r)
            op[(size_t)(ct * 16 + g * 4 + r) * N_ + m] = (bf16)acc[ct][r];
}

// ---------------------------------------------------------------------------
// K2: out[b,k][c][n] = sum_m ag[n,m]*xk[m,c], ag fused (never hits HBM).
//   Block = (b,k,n32). Phase 1: 256 threads build the 32x256 ag tile
//   (1 exp/element) into 16 KB XOR-swizzled LDS. Phase 2: wave w = c-tile w,
//   16 x mfma_32x32x16; A via swizzled ds_read_b128 (conflict-optimal),
//   B streamed from xkT (L2-hot). One barrier total.
//   xkT rows 100..111 are zeros; tile-3 overread past slice end lands in the
//   next slice / poisoned ws and feeds only never-stored columns c>=112.
// Grid 1280 XCD-swizzled blocks x 256 thr.
// ---------------------------------------------------------------------------
__global__ __launch_bounds__(256) void gauss_agg(
    const float* __restrict__ adj, const float* __restrict__ pseudo,
    const float* __restrict__ mu, const float* __restrict__ sigma,
    const bf16* __restrict__ xkT, float* __restrict__ out)
{
    __shared__ __align__(16) char lds[32 * 512];   // ag tile, 16B-chunk swizzle

    const int bid = blockIdx.x;
    const int xcd = bid & 7, s = bid >> 3;         // s: 0..159
    const int b  = xcd + 8 * (s / 80);
    const int rr = s % 80, kk = rr >> 3, nh = rr & 7;
    const int n32 = nh * 32;
    const int tid = threadIdx.x;

    // per-thread gaussian coefs (kk uniform -> scalar loads)
    float Av[4], Bv[4], ga = 0.0f;
    #pragma unroll
    for (int d = 0; d < 4; ++d) {
        float sg = sigma[kk * 4 + d];
        float al = NL2E / (1e-6f + sg * sg);
        float mv = mu[kk * 4 + d];
        Av[d] = al; Bv[d] = -2.0f * al * mv; ga += al * mv * mv;
    }

    // ---- phase 1: ag tile -> LDS ----
    const float* pbase = pseudo + (size_t)(b * N_ + n32) * N_ * 4;
    const float* abase = adj    + (size_t)(b * N_ + n32) * N_;
    #pragma unroll 4
    for (int i = 0; i < 8; ++i) {
        const int idx = i * 256 + tid;             // 0..2047 quads
        const int row = idx >> 6;                  // 0..31
        const int m0  = (idx & 63) * 4;
        const float* pp = pbase + ((size_t)row * N_ + m0) * 4;
        float4 p0 = *(const float4*)(pp + 0);
        float4 p1 = *(const float4*)(pp + 4);
        float4 p2 = *(const float4*)(pp + 8);
        float4 p3 = *(const float4*)(pp + 12);
        float4 av = *(const float4*)(abase + (size_t)row * N_ + m0);

        float s0 = ga + Av[0]*p0.x*p0.x + Bv[0]*p0.x + Av[1]*p0.y*p0.y + Bv[1]*p0.y
                      + Av[2]*p0.z*p0.z + Bv[2]*p0.z + Av[3]*p0.w*p0.w + Bv[3]*p0.w;
        float s1 = ga + Av[0]*p1.x*p1.x + Bv[0]*p1.x + Av[1]*p1.y*p1.y + Bv[1]*p1.y
                      + Av[2]*p1.z*p1.z + Bv[2]*p1.z + Av[3]*p1.w*p1.w + Bv[3]*p1.w;
        float s2 = ga + Av[0]*p2.x*p2.x + Bv[0]*p2.x + Av[1]*p2.y*p2.y + Bv[1]*p2.y
                      + Av[2]*p2.z*p2.z + Bv[2]*p2.z + Av[3]*p2.w*p2.w + Bv[3]*p2.w;
        float s3 = ga + Av[0]*p3.x*p3.x + Bv[0]*p3.x + Av[1]*p3.y*p3.y + Bv[1]*p3.y
                      + Av[2]*p3.z*p3.z + Bv[2]*p3.z + Av[3]*p3.w*p3.w + Bv[3]*p3.w;

        bf16x4 o = {(bf16)(__builtin_amdgcn_exp2f(s0) * av.x),
                    (bf16)(__builtin_amdgcn_exp2f(s1) * av.y),
                    (bf16)(__builtin_amdgcn_exp2f(s2) * av.z),
                    (bf16)(__builtin_amdgcn_exp2f(s3) * av.w)};
        const int ch = m0 >> 3, half = (m0 >> 2) & 1;
        *(bf16x4*)(lds + row * 512 + ((ch ^ (row & 7)) * 16) + half * 8) = o;
    }
    __syncthreads();

    // ---- phase 2: MFMA ----
    const int w = tid >> 6, l = tid & 63, l31 = l & 31, h = l >> 5;
    const bf16* brow = xkT + (size_t)(b * K_ + kk) * CP_ * N_
                           + (size_t)(w * 32 + l31) * N_;
    f32x16 acc;
    #pragma unroll
    for (int i = 0; i < 16; ++i) acc[i] = 0.0f;

    #pragma unroll
    for (int ks = 0; ks < 16; ++ks) {
        const int m0 = ks * 16 + h * 8;
        bf16x8 af = *(const bf16x8*)(lds + l31 * 512 + (((ks * 2 + h) ^ (l31 & 7)) * 16));
        bf16x8 bf = *(const bf16x8*)(brow + m0);
        acc = __builtin_amdgcn_mfma_f32_32x32x16_bf16(af, bf, acc, 0, 0, 0);
    }

    const int c = w * 32 + l31;
    if (c < C_) {
        float* ob = out + (size_t)(b * K_ + kk) * C_ * N_ + (size_t)c * N_ + n32;
        #pragma unroll
        for (int q = 0; q < 4; ++q) {
            float4 v = {acc[4*q+0], acc[4*q+1], acc[4*q+2], acc[4*q+3]};
            *(float4*)(ob + 8 * q + 4 * h) = v;
        }
    }
}

extern "C" void kernel_launch(void* const* d_in, const int* in_sizes, int n_in,
                              void* d_out, int out_size, void* d_ws, size_t ws_size,
                              hipStream_t stream)
{
    const float* x      = (const float*)d_in[0];
    const float* adj    = (const float*)d_in[1];
    const float* pseudo = (const float*)d_in[2];
    const float* mu     = (const float*)d_in[3];
    const float* sigma  = (const float*)d_in[4];
    const float* W      = (const float*)d_in[5];
    const float* bias   = (const float*)d_in[6];
    float* out = (float*)d_out;
    bf16* xkT  = (bf16*)d_ws;                      // 9.18 MB

    hipLaunchKernelGGL(xk_gemm, dim3(640), dim3(256), 0, stream, x, W, bias, xkT);
    hipLaunchKernelGGL(gauss_agg, dim3(1280), dim3(256), 0, stream,
                       adj, pseudo, mu, sigma, xkT, out);
}